// Round 1
// baseline (861.956 us; speedup 1.0000x reference)
//
#include <hip/hip_runtime.h>
#include <hip/hip_bf16.h>
#include <math.h>

#define NN 100000
#define EE 1600000
#define HD_ 128   // heads*hid = 4*32

// ---------------------------------------------------------------------------
// Kernel 1: fused projections  Q,K,V,S = x @ {Wq,Wk,Wv,Ws} + bias
// block = 256 threads, 16 nodes/block, 512 output cols.
// thread layout: ct = tid&63 -> 8 consecutive cols (within one matrix since
// 8 | 128); tn = tid>>6 -> 4 consecutive nodes. 32 acc regs/thread.
// x tile staged in LDS transposed [k][node] so compute reads are b128
// broadcasts; W rows streamed from global (256KB total -> L2 resident).
// ---------------------------------------------------------------------------
__global__ __launch_bounds__(256) void proj_kernel(
    const float* __restrict__ x,
    const float* __restrict__ Wq, const float* __restrict__ bq,
    const float* __restrict__ Wk, const float* __restrict__ bk,
    const float* __restrict__ Wv, const float* __restrict__ bv,
    const float* __restrict__ Ws, const float* __restrict__ bs,
    float* __restrict__ Q, float* __restrict__ K,
    float* __restrict__ V, float* __restrict__ S)
{
    __shared__ float xs[128 * 16];  // [k][node]
    const int tid = threadIdx.x;
    const int n0 = blockIdx.x * 16;

    // load 16 nodes x 128 k, transpose into LDS
    {
        const int node = tid >> 4;        // 0..15
        const int k0 = (tid & 15) * 8;    // 0..120
        const float4* xp = reinterpret_cast<const float4*>(x + (size_t)(n0 + node) * 128 + k0);
        float4 a = xp[0];
        float4 b = xp[1];
        xs[(k0 + 0) * 16 + node] = a.x;
        xs[(k0 + 1) * 16 + node] = a.y;
        xs[(k0 + 2) * 16 + node] = a.z;
        xs[(k0 + 3) * 16 + node] = a.w;
        xs[(k0 + 4) * 16 + node] = b.x;
        xs[(k0 + 5) * 16 + node] = b.y;
        xs[(k0 + 6) * 16 + node] = b.z;
        xs[(k0 + 7) * 16 + node] = b.w;
    }
    __syncthreads();

    const int ct = tid & 63;   // col group
    const int tn = tid >> 6;   // node group 0..3
    const int c = ct * 8;      // global col 0..504
    const int mid = c >> 7;    // which matrix
    const int cw = c & 127;    // col within matrix

    const float* Wm = (mid == 0) ? Wq : (mid == 1) ? Wk : (mid == 2) ? Wv : Ws;
    const float* bm = (mid == 0) ? bq : (mid == 1) ? bk : (mid == 2) ? bv : bs;
    float* Om       = (mid == 0) ? Q  : (mid == 1) ? K  : (mid == 2) ? V  : S;

    float acc[4][8];
#pragma unroll
    for (int i = 0; i < 4; ++i)
#pragma unroll
        for (int j = 0; j < 8; ++j) acc[i][j] = 0.f;

#pragma unroll 4
    for (int k = 0; k < 128; ++k) {
        float4 xv = *reinterpret_cast<const float4*>(&xs[k * 16 + tn * 4]);
        float4 w0 = *reinterpret_cast<const float4*>(Wm + k * 128 + cw);
        float4 w1 = *reinterpret_cast<const float4*>(Wm + k * 128 + cw + 4);
        float xr[4] = {xv.x, xv.y, xv.z, xv.w};
        float wr[8] = {w0.x, w0.y, w0.z, w0.w, w1.x, w1.y, w1.z, w1.w};
#pragma unroll
        for (int i = 0; i < 4; ++i)
#pragma unroll
            for (int j = 0; j < 8; ++j) acc[i][j] = fmaf(xr[i], wr[j], acc[i][j]);
    }

    float4 bb0 = *reinterpret_cast<const float4*>(bm + cw);
    float4 bb1 = *reinterpret_cast<const float4*>(bm + cw + 4);
#pragma unroll
    for (int i = 0; i < 4; ++i) {
        const int node = n0 + tn * 4 + i;
        float4 o0 = {acc[i][0] + bb0.x, acc[i][1] + bb0.y, acc[i][2] + bb0.z, acc[i][3] + bb0.w};
        float4 o1 = {acc[i][4] + bb1.x, acc[i][5] + bb1.y, acc[i][6] + bb1.z, acc[i][7] + bb1.w};
        float4* op = reinterpret_cast<float4*>(Om + (size_t)node * 128 + cw);
        op[0] = o0;
        op[1] = o1;
    }
}

// ---------------------------------------------------------------------------
// Kernel 2: degree histogram over dst
// ---------------------------------------------------------------------------
__global__ __launch_bounds__(256) void deg_kernel(const int* __restrict__ ei,
                                                  int* __restrict__ deg)
{
    int e = blockIdx.x * 256 + threadIdx.x;
    if (e < EE) atomicAdd(&deg[ei[EE + e]], 1);
}

// ---------------------------------------------------------------------------
// Kernel 3: exclusive scan of deg -> offs (also copied to cursor)
// single block of 1024 threads, chunked wave-shuffle scan
// ---------------------------------------------------------------------------
__global__ __launch_bounds__(1024) void scan_kernel(const int* __restrict__ deg,
                                                    int* __restrict__ offs,
                                                    int* __restrict__ cursor,
                                                    int n)
{
    __shared__ int wsum[16];
    __shared__ int chunk_total;
    const int lane = threadIdx.x & 63;
    const int wid = threadIdx.x >> 6;
    int base = 0;
    for (int start = 0; start < n; start += 1024) {
        int i = start + threadIdx.x;
        int v = (i < n) ? deg[i] : 0;
        int xv = v;
#pragma unroll
        for (int off = 1; off < 64; off <<= 1) {
            int t = __shfl_up(xv, off);
            if (lane >= off) xv += t;
        }
        if (lane == 63) wsum[wid] = xv;
        __syncthreads();
        if (threadIdx.x < 16) {
            int y = wsum[threadIdx.x];
#pragma unroll
            for (int off = 1; off < 16; off <<= 1) {
                int t = __shfl_up(y, off);
                if ((int)threadIdx.x >= off) y += t;
            }
            wsum[threadIdx.x] = y;
            if (threadIdx.x == 15) chunk_total = y;
        }
        __syncthreads();
        int wbase = (wid > 0) ? wsum[wid - 1] : 0;
        int excl = base + wbase + xv - v;
        if (i < n) {
            offs[i] = excl;
            cursor[i] = excl;
        }
        base += chunk_total;
        __syncthreads();  // protect wsum/chunk_total before next iter
    }
}

// ---------------------------------------------------------------------------
// Kernel 4: scatter edges into dst-sorted order (store src index)
// ---------------------------------------------------------------------------
__global__ __launch_bounds__(256) void scatter_kernel(const int* __restrict__ ei,
                                                      int* __restrict__ cursor,
                                                      int* __restrict__ ssrc)
{
    int e = blockIdx.x * 256 + threadIdx.x;
    if (e < EE) {
        int dst = ei[EE + e];
        int pos = atomicAdd(&cursor[dst], 1);
        ssrc[pos] = ei[e];
    }
}

// ---------------------------------------------------------------------------
// Kernel 5: per-node online-softmax attention + skip + tanh + readout MLP
// one wave (64 lanes) per node; lane = h*16 + i covers dims {2i, 2i+1} of
// head h. Per edge: coalesced 512B loads of k[src], v[src]; per-head dot via
// shfl_xor reduce over the 16-lane group; online softmax rescale.
// ---------------------------------------------------------------------------
__global__ __launch_bounds__(256) void attn_kernel(
    const float* __restrict__ Q, const float* __restrict__ K,
    const float* __restrict__ V, const float* __restrict__ S,
    const int* __restrict__ offs, const int* __restrict__ deg,
    const int* __restrict__ ssrc,
    const float* __restrict__ W1, const float* __restrict__ b1,
    const float* __restrict__ W2, const float* __restrict__ b2,
    const float* __restrict__ W3, const float* __restrict__ b3,
    float* __restrict__ out)
{
    const int wid = threadIdx.x >> 6;
    const int lane = threadIdx.x & 63;
    const int node = blockIdx.x * 4 + wid;

    __shared__ float hs[4][128];
    __shared__ float h1s[4][24];
    __shared__ float h2s[4][8];

    const float q0 = Q[(size_t)node * 128 + lane * 2];
    const float q1 = Q[(size_t)node * 128 + lane * 2 + 1];
    const float scale = 0.17677669529663687f;  // 1/sqrt(32)

    float m = -INFINITY, l = 0.f, a0 = 0.f, a1 = 0.f;
    const int st = offs[node];
    const int en = st + deg[node];

    for (int ii = st; ii < en; ++ii) {
        const int src = ssrc[ii];
        const float2 k2 = *reinterpret_cast<const float2*>(K + (size_t)src * 128 + lane * 2);
        float p = q0 * k2.x + q1 * k2.y;
        p += __shfl_xor(p, 1);
        p += __shfl_xor(p, 2);
        p += __shfl_xor(p, 4);
        p += __shfl_xor(p, 8);
        p *= scale;
        const float2 v2 = *reinterpret_cast<const float2*>(V + (size_t)src * 128 + lane * 2);
        const float nm = fmaxf(m, p);
        const float f = __expf(m - nm);   // 0 on first edge (m = -inf)
        const float w = __expf(p - nm);
        l = l * f + w;
        a0 = a0 * f + w * v2.x;
        a1 = a1 * f + w * v2.y;
        m = nm;
    }

    const float inv = (l > 0.f) ? 1.f / l : 0.f;
    const float s0 = S[(size_t)node * 128 + lane * 2];
    const float s1 = S[(size_t)node * 128 + lane * 2 + 1];
    hs[wid][lane * 2]     = tanhf(a0 * inv + s0);
    hs[wid][lane * 2 + 1] = tanhf(a1 * inv + s1);
    __syncthreads();

    if (lane < 24) {
        float t = b1[lane];
#pragma unroll 8
        for (int kk = 0; kk < 128; ++kk) t = fmaf(hs[wid][kk], W1[kk * 24 + lane], t);
        h1s[wid][lane] = t - tanhf(t);
    }
    __syncthreads();

    if (lane < 8) {
        float u = b2[lane];
#pragma unroll
        for (int kk = 0; kk < 24; ++kk) u = fmaf(h1s[wid][kk], W2[kk * 8 + lane], u);
        h2s[wid][lane] = u - tanhf(u);
    }
    __syncthreads();

    if (lane < 2) {
        float o = b3[lane];
#pragma unroll
        for (int kk = 0; kk < 8; ++kk) o = fmaf(h2s[wid][kk], W3[kk * 2 + lane], o);
        out[(size_t)node * 2 + lane] = o;
    }
}

// ---------------------------------------------------------------------------
extern "C" void kernel_launch(void* const* d_in, const int* in_sizes, int n_in,
                              void* d_out, int out_size, void* d_ws, size_t ws_size,
                              hipStream_t stream)
{
    const float* x  = (const float*)d_in[0];
    const int*   ei = (const int*)d_in[1];
    const float* Wq = (const float*)d_in[2];
    const float* bq = (const float*)d_in[3];
    const float* Wk = (const float*)d_in[4];
    const float* bk = (const float*)d_in[5];
    const float* Wv = (const float*)d_in[6];
    const float* bv = (const float*)d_in[7];
    const float* Ws = (const float*)d_in[8];
    const float* bs = (const float*)d_in[9];
    const float* W1 = (const float*)d_in[10];
    const float* b1 = (const float*)d_in[11];
    const float* W2 = (const float*)d_in[12];
    const float* b2 = (const float*)d_in[13];
    const float* W3 = (const float*)d_in[14];
    const float* b3 = (const float*)d_in[15];
    float* out = (float*)d_out;

    float* ws = (float*)d_ws;
    float* Q = ws;
    float* K = Q + (size_t)NN * HD_;
    float* V = K + (size_t)NN * HD_;
    float* S = V + (size_t)NN * HD_;
    int* deg    = (int*)(S + (size_t)NN * HD_);
    int* offs   = deg + NN;
    int* cursor = offs + NN;
    int* ssrc   = cursor + NN;

    hipMemsetAsync(deg, 0, NN * sizeof(int), stream);

    proj_kernel<<<NN / 16, 256, 0, stream>>>(x, Wq, bq, Wk, bk, Wv, bv, Ws, bs,
                                             Q, K, V, S);
    deg_kernel<<<(EE + 255) / 256, 256, 0, stream>>>(ei, deg);
    scan_kernel<<<1, 1024, 0, stream>>>(deg, offs, cursor, NN);
    scatter_kernel<<<(EE + 255) / 256, 256, 0, stream>>>(ei, cursor, ssrc);
    attn_kernel<<<NN / 4, 256, 0, stream>>>(Q, K, V, S, offs, deg, ssrc,
                                            W1, b1, W2, b2, W3, b3, out);
}

// Round 2
// 714.154 us; speedup vs baseline: 1.2070x; 1.2070x over previous
//
#include <hip/hip_runtime.h>
#include <hip/hip_bf16.h>
#include <hip/hip_fp16.h>
#include <math.h>

#define NN 100000
#define EE 1600000
#define HD_ 128   // heads*hid = 4*32
#define NT 32     // nodes per proj block

// ---------------------------------------------------------------------------
// fast tanh via hardware exp, overflow-safe form
// ---------------------------------------------------------------------------
__device__ __forceinline__ float fast_tanh(float z) {
    float az = fabsf(z);
    float e = __expf(-2.f * az);
    float t = (1.f - e) / (1.f + e);
    return copysignf(t, z);
}

// ---------------------------------------------------------------------------
// Kernel 1: fused projections. block = 256 = 4 waves; wave w owns matrix w
// (0:Q, 1:K, 2:V, 3:S). 32 nodes/block. Each block reads W exactly once.
// x tile transposed in LDS [k][node] with pad 36 (16B-aligned rows, 2-way
// write aliasing only). K,V emitted as fp16 into combined KV[node][256]
// (k = cols 0..127, v = cols 128..255).
// ---------------------------------------------------------------------------
__global__ __launch_bounds__(256) void proj_kernel(
    const float* __restrict__ x,
    const float* __restrict__ Wq, const float* __restrict__ bq,
    const float* __restrict__ Wk, const float* __restrict__ bk,
    const float* __restrict__ Wv, const float* __restrict__ bv,
    const float* __restrict__ Ws, const float* __restrict__ bs,
    float* __restrict__ Q, float* __restrict__ S, __half* __restrict__ KV)
{
    __shared__ float xs[128][36];
    const int tid = threadIdx.x;
    const int n0 = blockIdx.x * NT;

    // load 32 nodes x 128 k, transpose into LDS
    {
        const int node = tid & 31;
        const int k0 = (tid >> 5) * 16;
        const float4* xp = reinterpret_cast<const float4*>(
            x + (size_t)(n0 + node) * 128 + k0);
#pragma unroll
        for (int j = 0; j < 4; ++j) {
            float4 a = xp[j];
            xs[k0 + j * 4 + 0][node] = a.x;
            xs[k0 + j * 4 + 1][node] = a.y;
            xs[k0 + j * 4 + 2][node] = a.z;
            xs[k0 + j * 4 + 3][node] = a.w;
        }
    }
    __syncthreads();

    const int w = tid >> 6;     // which matrix
    const int lane = tid & 63;
    const int c = lane * 2;     // 2 consecutive cols per lane

    const float* Wm = (w == 0) ? Wq : (w == 1) ? Wk : (w == 2) ? Wv : Ws;
    const float* bm = (w == 0) ? bq : (w == 1) ? bk : (w == 2) ? bv : bs;

    float2 acc[NT];
#pragma unroll
    for (int n = 0; n < NT; ++n) acc[n] = make_float2(0.f, 0.f);

#pragma unroll 4
    for (int k = 0; k < 128; ++k) {
        const float2 wv = *reinterpret_cast<const float2*>(Wm + k * 128 + c);
#pragma unroll
        for (int j = 0; j < 8; ++j) {
            float4 xv = *reinterpret_cast<const float4*>(&xs[k][j * 4]);
            acc[j * 4 + 0].x = fmaf(xv.x, wv.x, acc[j * 4 + 0].x);
            acc[j * 4 + 0].y = fmaf(xv.x, wv.y, acc[j * 4 + 0].y);
            acc[j * 4 + 1].x = fmaf(xv.y, wv.x, acc[j * 4 + 1].x);
            acc[j * 4 + 1].y = fmaf(xv.y, wv.y, acc[j * 4 + 1].y);
            acc[j * 4 + 2].x = fmaf(xv.z, wv.x, acc[j * 4 + 2].x);
            acc[j * 4 + 2].y = fmaf(xv.z, wv.y, acc[j * 4 + 2].y);
            acc[j * 4 + 3].x = fmaf(xv.w, wv.x, acc[j * 4 + 3].x);
            acc[j * 4 + 3].y = fmaf(xv.w, wv.y, acc[j * 4 + 3].y);
        }
    }

    const float2 bb = *reinterpret_cast<const float2*>(bm + c);
    if (w == 0 || w == 3) {
        float* Om = (w == 0) ? Q : S;
#pragma unroll 4
        for (int n = 0; n < NT; ++n) {
            float2 o = make_float2(acc[n].x + bb.x, acc[n].y + bb.y);
            *reinterpret_cast<float2*>(Om + (size_t)(n0 + n) * 128 + c) = o;
        }
    } else {
        __half* Om = KV + ((w == 1) ? 0 : 128);
#pragma unroll 4
        for (int n = 0; n < NT; ++n) {
            *reinterpret_cast<__half2*>(Om + (size_t)(n0 + n) * 256 + c) =
                __floats2half2_rn(acc[n].x + bb.x, acc[n].y + bb.y);
        }
    }
}

// ---------------------------------------------------------------------------
// Kernel 2: degree histogram over dst
// ---------------------------------------------------------------------------
__global__ __launch_bounds__(256) void deg_kernel(const int* __restrict__ ei,
                                                  int* __restrict__ deg)
{
    int e = blockIdx.x * 256 + threadIdx.x;
    if (e < EE) atomicAdd(&deg[ei[EE + e]], 1);
}

// ---------------------------------------------------------------------------
// Kernels 3a/3b/3c: hierarchical exclusive scan of deg -> offs (+cursor copy)
// 1024 elems per scanA block (256 thr x 4), 98 blocks; scanB scans the 98
// block totals in one block; scanC adds bases and fans out.
// ---------------------------------------------------------------------------
#define SC_BLK 1024
#define SC_NB ((NN + SC_BLK - 1) / SC_BLK)   // 98

__global__ __launch_bounds__(256) void scanA_kernel(const int* __restrict__ deg,
                                                    int* __restrict__ offs,
                                                    int* __restrict__ bsum)
{
    __shared__ int wsum[4];
    const int tid = threadIdx.x;
    const int lane = tid & 63;
    const int wid = tid >> 6;
    const int base = blockIdx.x * SC_BLK + tid * 4;

    int v[4];
#pragma unroll
    for (int j = 0; j < 4; ++j) v[j] = (base + j < NN) ? deg[base + j] : 0;
    int s = v[0] + v[1] + v[2] + v[3];

    int inc = s;
#pragma unroll
    for (int off = 1; off < 64; off <<= 1) {
        int t = __shfl_up(inc, off);
        if (lane >= off) inc += t;
    }
    if (lane == 63) wsum[wid] = inc;
    __syncthreads();

    int wbase = 0;
    if (wid > 0) wbase += wsum[0];
    if (wid > 1) wbase += wsum[1];
    if (wid > 2) wbase += wsum[2];

    int excl = wbase + inc - s;
#pragma unroll
    for (int j = 0; j < 4; ++j) {
        if (base + j < NN) offs[base + j] = excl;
        excl += v[j];
    }
    if (tid == 255) bsum[blockIdx.x] = wbase + inc;
}

__global__ __launch_bounds__(128) void scanB_kernel(int* __restrict__ bsum)
{
    __shared__ int w0;
    const int tid = threadIdx.x;
    const int lane = tid & 63;
    int v = (tid < SC_NB) ? bsum[tid] : 0;
    int inc = v;
#pragma unroll
    for (int off = 1; off < 64; off <<= 1) {
        int t = __shfl_up(inc, off);
        if (lane >= off) inc += t;
    }
    if (tid == 63) w0 = inc;
    __syncthreads();
    int excl = inc - v + ((tid >= 64) ? w0 : 0);
    if (tid < SC_NB) bsum[tid] = excl;
}

__global__ __launch_bounds__(256) void scanC_kernel(int* __restrict__ offs,
                                                    const int* __restrict__ bsum,
                                                    int* __restrict__ cursor)
{
    int i = blockIdx.x * 256 + threadIdx.x;
    if (i < NN) {
        int v = offs[i] + bsum[i >> 10];
        offs[i] = v;
        cursor[i] = v;
    }
}

// ---------------------------------------------------------------------------
// Kernel 4: scatter edges into dst-sorted order (store src index)
// ---------------------------------------------------------------------------
__global__ __launch_bounds__(256) void scatter_kernel(const int* __restrict__ ei,
                                                      int* __restrict__ cursor,
                                                      int* __restrict__ ssrc)
{
    int e = blockIdx.x * 256 + threadIdx.x;
    if (e < EE) {
        int dst = ei[EE + e];
        int pos = atomicAdd(&cursor[dst], 1);
        ssrc[pos] = ei[e];
    }
}

// ---------------------------------------------------------------------------
// Kernel 5: per-node online-softmax attention + skip + tanh + readout MLP.
// One wave per node; lane = h*16+i covers dims {2i,2i+1} of head h.
// K/V gathered as fp16 (256B per row), converted to f32 in-register.
// ---------------------------------------------------------------------------
__global__ __launch_bounds__(256) void attn_kernel(
    const float* __restrict__ Q, const __half* __restrict__ KV,
    const float* __restrict__ S,
    const int* __restrict__ offs, const int* __restrict__ deg,
    const int* __restrict__ ssrc,
    const float* __restrict__ W1, const float* __restrict__ b1,
    const float* __restrict__ W2, const float* __restrict__ b2,
    const float* __restrict__ W3, const float* __restrict__ b3,
    float* __restrict__ out)
{
    const int wid = threadIdx.x >> 6;
    const int lane = threadIdx.x & 63;
    const int node = blockIdx.x * 4 + wid;

    __shared__ float hs[4][128];
    __shared__ float h1s[4][24];
    __shared__ float h2s[4][8];

    const float q0 = Q[(size_t)node * 128 + lane * 2];
    const float q1 = Q[(size_t)node * 128 + lane * 2 + 1];
    const float scale = 0.17677669529663687f;  // 1/sqrt(32)

    float m = -INFINITY, l = 0.f, a0 = 0.f, a1 = 0.f;
    const int st = offs[node];
    const int en = st + deg[node];

    for (int ii = st; ii < en; ++ii) {
        const int src = ssrc[ii];
        const float2 k2 = __half22float2(
            *reinterpret_cast<const __half2*>(KV + (size_t)src * 256 + lane * 2));
        float p = q0 * k2.x + q1 * k2.y;
        p += __shfl_xor(p, 1);
        p += __shfl_xor(p, 2);
        p += __shfl_xor(p, 4);
        p += __shfl_xor(p, 8);
        p *= scale;
        const float2 v2 = __half22float2(
            *reinterpret_cast<const __half2*>(KV + (size_t)src * 256 + 128 + lane * 2));
        const float nm = fmaxf(m, p);
        const float f = __expf(m - nm);   // 0 on first edge (m = -inf)
        const float w = __expf(p - nm);
        l = l * f + w;
        a0 = a0 * f + w * v2.x;
        a1 = a1 * f + w * v2.y;
        m = nm;
    }

    const float inv = (l > 0.f) ? 1.f / l : 0.f;
    const float s0 = S[(size_t)node * 128 + lane * 2];
    const float s1 = S[(size_t)node * 128 + lane * 2 + 1];
    hs[wid][lane * 2]     = fast_tanh(a0 * inv + s0);
    hs[wid][lane * 2 + 1] = fast_tanh(a1 * inv + s1);
    __syncthreads();

    if (lane < 24) {
        float t = b1[lane];
#pragma unroll 8
        for (int kk = 0; kk < 128; ++kk) t = fmaf(hs[wid][kk], W1[kk * 24 + lane], t);
        h1s[wid][lane] = t - fast_tanh(t);
    }
    __syncthreads();

    if (lane < 8) {
        float u = b2[lane];
#pragma unroll
        for (int kk = 0; kk < 24; ++kk) u = fmaf(h1s[wid][kk], W2[kk * 8 + lane], u);
        h2s[wid][lane] = u - fast_tanh(u);
    }
    __syncthreads();

    if (lane < 2) {
        float o = b3[lane];
#pragma unroll
        for (int kk = 0; kk < 8; ++kk) o = fmaf(h2s[wid][kk], W3[kk * 2 + lane], o);
        out[(size_t)node * 2 + lane] = o;
    }
}

// ---------------------------------------------------------------------------
extern "C" void kernel_launch(void* const* d_in, const int* in_sizes, int n_in,
                              void* d_out, int out_size, void* d_ws, size_t ws_size,
                              hipStream_t stream)
{
    const float* x  = (const float*)d_in[0];
    const int*   ei = (const int*)d_in[1];
    const float* Wq = (const float*)d_in[2];
    const float* bq = (const float*)d_in[3];
    const float* Wk = (const float*)d_in[4];
    const float* bk = (const float*)d_in[5];
    const float* Wv = (const float*)d_in[6];
    const float* bv = (const float*)d_in[7];
    const float* Ws = (const float*)d_in[8];
    const float* bs = (const float*)d_in[9];
    const float* W1 = (const float*)d_in[10];
    const float* b1 = (const float*)d_in[11];
    const float* W2 = (const float*)d_in[12];
    const float* b2 = (const float*)d_in[13];
    const float* W3 = (const float*)d_in[14];
    const float* b3 = (const float*)d_in[15];
    float* out = (float*)d_out;

    float* ws = (float*)d_ws;
    float* Q = ws;
    float* S = Q + (size_t)NN * HD_;
    __half* KV = (__half*)(S + (size_t)NN * HD_);
    int* deg    = (int*)(KV + (size_t)NN * 256);
    int* offs   = deg + NN;
    int* cursor = offs + NN;
    int* ssrc   = cursor + NN;
    int* bsum   = ssrc + EE;

    hipMemsetAsync(deg, 0, NN * sizeof(int), stream);

    proj_kernel<<<NN / NT, 256, 0, stream>>>(x, Wq, bq, Wk, bk, Wv, bv, Ws, bs,
                                             Q, S, KV);
    deg_kernel<<<(EE + 255) / 256, 256, 0, stream>>>(ei, deg);
    scanA_kernel<<<SC_NB, 256, 0, stream>>>(deg, offs, bsum);
    scanB_kernel<<<1, 128, 0, stream>>>(bsum);
    scanC_kernel<<<(NN + 255) / 256, 256, 0, stream>>>(offs, bsum, cursor);
    scatter_kernel<<<(EE + 255) / 256, 256, 0, stream>>>(ei, cursor, ssrc);
    attn_kernel<<<NN / 4, 256, 0, stream>>>(Q, KV, S, offs, deg, ssrc,
                                            W1, b1, W2, b2, W3, b3, out);
}

// Round 3
// 607.429 us; speedup vs baseline: 1.4190x; 1.1757x over previous
//
#include <hip/hip_runtime.h>
#include <hip/hip_bf16.h>
#include <hip/hip_fp16.h>
#include <math.h>

#define NN 100000
#define EE 1600000
#define HD_ 128   // heads*hid = 4*32
#define NT 32     // nodes per proj block

// ---------------------------------------------------------------------------
// fast tanh via hardware exp, overflow-safe form
// ---------------------------------------------------------------------------
__device__ __forceinline__ float fast_tanh(float z) {
    float az = fabsf(z);
    float e = __expf(-2.f * az);
    float t = (1.f - e) / (1.f + e);
    return copysignf(t, z);
}

struct alignas(16) h8 { __half2 h[4]; };  // 8 halves = 16B

// ---------------------------------------------------------------------------
// Kernel 1: fused projections. block = 256 = 4 waves; wave w owns matrix w
// (0:Q, 1:K, 2:V, 3:S). 32 nodes/block. Each block reads W exactly once.
// K,V emitted as fp16 into combined KV[node][256] (k: 0..127, v: 128..255).
// ---------------------------------------------------------------------------
__global__ __launch_bounds__(256) void proj_kernel(
    const float* __restrict__ x,
    const float* __restrict__ Wq, const float* __restrict__ bq,
    const float* __restrict__ Wk, const float* __restrict__ bk,
    const float* __restrict__ Wv, const float* __restrict__ bv,
    const float* __restrict__ Ws, const float* __restrict__ bs,
    float* __restrict__ Q, float* __restrict__ S, __half* __restrict__ KV)
{
    __shared__ float xs[128][36];
    const int tid = threadIdx.x;
    const int n0 = blockIdx.x * NT;

    // load 32 nodes x 128 k, transpose into LDS
    {
        const int node = tid & 31;
        const int k0 = (tid >> 5) * 16;
        const float4* xp = reinterpret_cast<const float4*>(
            x + (size_t)(n0 + node) * 128 + k0);
#pragma unroll
        for (int j = 0; j < 4; ++j) {
            float4 a = xp[j];
            xs[k0 + j * 4 + 0][node] = a.x;
            xs[k0 + j * 4 + 1][node] = a.y;
            xs[k0 + j * 4 + 2][node] = a.z;
            xs[k0 + j * 4 + 3][node] = a.w;
        }
    }
    __syncthreads();

    const int w = tid >> 6;     // which matrix
    const int lane = tid & 63;
    const int c = lane * 2;     // 2 consecutive cols per lane

    const float* Wm = (w == 0) ? Wq : (w == 1) ? Wk : (w == 2) ? Wv : Ws;
    const float* bm = (w == 0) ? bq : (w == 1) ? bk : (w == 2) ? bv : bs;

    float2 acc[NT];
#pragma unroll
    for (int n = 0; n < NT; ++n) acc[n] = make_float2(0.f, 0.f);

#pragma unroll 4
    for (int k = 0; k < 128; ++k) {
        const float2 wv = *reinterpret_cast<const float2*>(Wm + k * 128 + c);
#pragma unroll
        for (int j = 0; j < 8; ++j) {
            float4 xv = *reinterpret_cast<const float4*>(&xs[k][j * 4]);
            acc[j * 4 + 0].x = fmaf(xv.x, wv.x, acc[j * 4 + 0].x);
            acc[j * 4 + 0].y = fmaf(xv.x, wv.y, acc[j * 4 + 0].y);
            acc[j * 4 + 1].x = fmaf(xv.y, wv.x, acc[j * 4 + 1].x);
            acc[j * 4 + 1].y = fmaf(xv.y, wv.y, acc[j * 4 + 1].y);
            acc[j * 4 + 2].x = fmaf(xv.z, wv.x, acc[j * 4 + 2].x);
            acc[j * 4 + 2].y = fmaf(xv.z, wv.y, acc[j * 4 + 2].y);
            acc[j * 4 + 3].x = fmaf(xv.w, wv.x, acc[j * 4 + 3].x);
            acc[j * 4 + 3].y = fmaf(xv.w, wv.y, acc[j * 4 + 3].y);
        }
    }

    const float2 bb = *reinterpret_cast<const float2*>(bm + c);
    if (w == 0 || w == 3) {
        float* Om = (w == 0) ? Q : S;
#pragma unroll 4
        for (int n = 0; n < NT; ++n) {
            float2 o = make_float2(acc[n].x + bb.x, acc[n].y + bb.y);
            *reinterpret_cast<float2*>(Om + (size_t)(n0 + n) * 128 + c) = o;
        }
    } else {
        __half* Om = KV + ((w == 1) ? 0 : 128);
#pragma unroll 4
        for (int n = 0; n < NT; ++n) {
            *reinterpret_cast<__half2*>(Om + (size_t)(n0 + n) * 256 + c) =
                __floats2half2_rn(acc[n].x + bb.x, acc[n].y + bb.y);
        }
    }
}

// ---------------------------------------------------------------------------
// Kernel 2: degree histogram over dst
// ---------------------------------------------------------------------------
__global__ __launch_bounds__(256) void deg_kernel(const int* __restrict__ ei,
                                                  int* __restrict__ deg)
{
    int e = blockIdx.x * 256 + threadIdx.x;
    if (e < EE) atomicAdd(&deg[ei[EE + e]], 1);
}

// ---------------------------------------------------------------------------
// Kernels 3a/3b/3c: hierarchical exclusive scan of deg -> offs (+cursor copy)
// ---------------------------------------------------------------------------
#define SC_BLK 1024
#define SC_NB ((NN + SC_BLK - 1) / SC_BLK)   // 98

__global__ __launch_bounds__(256) void scanA_kernel(const int* __restrict__ deg,
                                                    int* __restrict__ offs,
                                                    int* __restrict__ bsum)
{
    __shared__ int wsum[4];
    const int tid = threadIdx.x;
    const int lane = tid & 63;
    const int wid = tid >> 6;
    const int base = blockIdx.x * SC_BLK + tid * 4;

    int v[4];
#pragma unroll
    for (int j = 0; j < 4; ++j) v[j] = (base + j < NN) ? deg[base + j] : 0;
    int s = v[0] + v[1] + v[2] + v[3];

    int inc = s;
#pragma unroll
    for (int off = 1; off < 64; off <<= 1) {
        int t = __shfl_up(inc, off);
        if (lane >= off) inc += t;
    }
    if (lane == 63) wsum[wid] = inc;
    __syncthreads();

    int wbase = 0;
    if (wid > 0) wbase += wsum[0];
    if (wid > 1) wbase += wsum[1];
    if (wid > 2) wbase += wsum[2];

    int excl = wbase + inc - s;
#pragma unroll
    for (int j = 0; j < 4; ++j) {
        if (base + j < NN) offs[base + j] = excl;
        excl += v[j];
    }
    if (tid == 255) bsum[blockIdx.x] = wbase + inc;
}

__global__ __launch_bounds__(128) void scanB_kernel(int* __restrict__ bsum)
{
    __shared__ int w0;
    const int tid = threadIdx.x;
    const int lane = tid & 63;
    int v = (tid < SC_NB) ? bsum[tid] : 0;
    int inc = v;
#pragma unroll
    for (int off = 1; off < 64; off <<= 1) {
        int t = __shfl_up(inc, off);
        if (lane >= off) inc += t;
    }
    if (tid == 63) w0 = inc;
    __syncthreads();
    int excl = inc - v + ((tid >= 64) ? w0 : 0);
    if (tid < SC_NB) bsum[tid] = excl;
}

__global__ __launch_bounds__(256) void scanC_kernel(int* __restrict__ offs,
                                                    const int* __restrict__ bsum,
                                                    int* __restrict__ cursor)
{
    int i = blockIdx.x * 256 + threadIdx.x;
    if (i < NN) {
        int v = offs[i] + bsum[i >> 10];
        offs[i] = v;
        cursor[i] = v;
    }
}

// ---------------------------------------------------------------------------
// Kernel 4: scatter edges into dst-sorted order (store src index)
// ---------------------------------------------------------------------------
__global__ __launch_bounds__(256) void scatter_kernel(const int* __restrict__ ei,
                                                      int* __restrict__ cursor,
                                                      int* __restrict__ ssrc)
{
    int e = blockIdx.x * 256 + threadIdx.x;
    if (e < EE) {
        int dst = ei[EE + e];
        int pos = atomicAdd(&cursor[dst], 1);
        ssrc[pos] = ei[e];
    }
}

// ---------------------------------------------------------------------------
// Kernel 5: per-node attention (no-max softmax: scores bounded |p|<~2) +
// skip + tanh + readout MLP.
// One wave per node. Lane layout: eg = lane>>4 (edge slot 0..3),
// li = lane&15 (row position, dims 8*li..8*li+7; head = li>>2).
// Per iteration the wave processes 4 edges; each lane loads 16B of K and 16B
// of V (1KB coalesced per load instr). Dot-reduce: 2 shfl_xor within quads.
// Cross-slot combine (xor 16,32) once at the end.
// ---------------------------------------------------------------------------
__global__ __launch_bounds__(256) void attn_kernel(
    const float* __restrict__ Q, const __half* __restrict__ KV,
    const float* __restrict__ S,
    const int* __restrict__ offs, const int* __restrict__ deg,
    const int* __restrict__ ssrc,
    const float* __restrict__ W1, const float* __restrict__ b1,
    const float* __restrict__ W2, const float* __restrict__ b2,
    const float* __restrict__ W3, const float* __restrict__ b3,
    float* __restrict__ out)
{
    const int wid = threadIdx.x >> 6;
    const int lane = threadIdx.x & 63;
    const int node = blockIdx.x * 4 + wid;
    const int eg = lane >> 4;   // edge slot
    const int li = lane & 15;   // position within row

    __shared__ float hs[4][128];
    __shared__ float h1s[4][24];
    __shared__ float h2s[4][8];

    const float scale = 0.17677669529663687f;  // 1/sqrt(32)

    // q dims 8*li .. 8*li+7, pre-scaled
    float qf[8];
    {
        const float4 qa = *reinterpret_cast<const float4*>(Q + (size_t)node * 128 + li * 8);
        const float4 qb = *reinterpret_cast<const float4*>(Q + (size_t)node * 128 + li * 8 + 4);
        qf[0] = qa.x * scale; qf[1] = qa.y * scale;
        qf[2] = qa.z * scale; qf[3] = qa.w * scale;
        qf[4] = qb.x * scale; qf[5] = qb.y * scale;
        qf[6] = qb.z * scale; qf[7] = qb.w * scale;
    }

    float a[8];
#pragma unroll
    for (int j = 0; j < 8; ++j) a[j] = 0.f;
    float l = 0.f;

    const int st = offs[node];
    const int dg = deg[node];
    const int voff = li * 16;  // byte-ish offset in halves: li*16 halves = 32B.. (indexing in halves below)

    for (int it = 0; it < dg; it += 4) {
        const int e = it + eg;
        const bool valid = e < dg;
        const int src = ssrc[valid ? (st + e) : st];
        const __half* row = KV + (size_t)src * 256 + li * 8;

        const h8 kk = *reinterpret_cast<const h8*>(row);
        float p = 0.f;
#pragma unroll
        for (int j = 0; j < 4; ++j) {
            const float2 kf = __half22float2(kk.h[j]);
            p = fmaf(qf[2 * j], kf.x, p);
            p = fmaf(qf[2 * j + 1], kf.y, p);
        }
        p += __shfl_xor(p, 1);
        p += __shfl_xor(p, 2);   // now each lane has its head's full score

        float w = valid ? __expf(p) : 0.f;

        const h8 vv = *reinterpret_cast<const h8*>(row + 128);
        l += w;
#pragma unroll
        for (int j = 0; j < 4; ++j) {
            const float2 vf = __half22float2(vv.h[j]);
            a[2 * j]     = fmaf(w, vf.x, a[2 * j]);
            a[2 * j + 1] = fmaf(w, vf.y, a[2 * j + 1]);
        }
    }
    (void)voff;

    // combine the 4 edge slots
#pragma unroll
    for (int j = 0; j < 8; ++j) {
        a[j] += __shfl_xor(a[j], 16);
        a[j] += __shfl_xor(a[j], 32);
    }
    l += __shfl_xor(l, 16);
    l += __shfl_xor(l, 32);

    const float inv = (l > 0.f) ? 1.f / l : 0.f;

    if (eg == 0) {
        const float4 sa = *reinterpret_cast<const float4*>(S + (size_t)node * 128 + li * 8);
        const float4 sb = *reinterpret_cast<const float4*>(S + (size_t)node * 128 + li * 8 + 4);
        const float sf[8] = {sa.x, sa.y, sa.z, sa.w, sb.x, sb.y, sb.z, sb.w};
#pragma unroll
        for (int j = 0; j < 8; ++j)
            hs[wid][li * 8 + j] = fast_tanh(a[j] * inv + sf[j]);
    }
    __syncthreads();

    if (lane < 24) {
        float t = b1[lane];
#pragma unroll 8
        for (int kk = 0; kk < 128; ++kk) t = fmaf(hs[wid][kk], W1[kk * 24 + lane], t);
        h1s[wid][lane] = t - fast_tanh(t);
    }
    __syncthreads();

    if (lane < 8) {
        float u = b2[lane];
#pragma unroll
        for (int kk = 0; kk < 24; ++kk) u = fmaf(h1s[wid][kk], W2[kk * 8 + lane], u);
        h2s[wid][lane] = u - fast_tanh(u);
    }
    __syncthreads();

    if (lane < 2) {
        float o = b3[lane];
#pragma unroll
        for (int kk = 0; kk < 8; ++kk) o = fmaf(h2s[wid][kk], W3[kk * 2 + lane], o);
        out[(size_t)node * 2 + lane] = o;
    }
}

// ---------------------------------------------------------------------------
extern "C" void kernel_launch(void* const* d_in, const int* in_sizes, int n_in,
                              void* d_out, int out_size, void* d_ws, size_t ws_size,
                              hipStream_t stream)
{
    const float* x  = (const float*)d_in[0];
    const int*   ei = (const int*)d_in[1];
    const float* Wq = (const float*)d_in[2];
    const float* bq = (const float*)d_in[3];
    const float* Wk = (const float*)d_in[4];
    const float* bk = (const float*)d_in[5];
    const float* Wv = (const float*)d_in[6];
    const float* bv = (const float*)d_in[7];
    const float* Ws = (const float*)d_in[8];
    const float* bs = (const float*)d_in[9];
    const float* W1 = (const float*)d_in[10];
    const float* b1 = (const float*)d_in[11];
    const float* W2 = (const float*)d_in[12];
    const float* b2 = (const float*)d_in[13];
    const float* W3 = (const float*)d_in[14];
    const float* b3 = (const float*)d_in[15];
    float* out = (float*)d_out;

    float* ws = (float*)d_ws;
    float* Q = ws;
    float* S = Q + (size_t)NN * HD_;
    __half* KV = (__half*)(S + (size_t)NN * HD_);
    int* deg    = (int*)(KV + (size_t)NN * 256);
    int* offs   = deg + NN;
    int* cursor = offs + NN;
    int* ssrc   = cursor + NN;
    int* bsum   = ssrc + EE;

    hipMemsetAsync(deg, 0, NN * sizeof(int), stream);

    proj_kernel<<<NN / NT, 256, 0, stream>>>(x, Wq, bq, Wk, bk, Wv, bv, Ws, bs,
                                             Q, S, KV);
    deg_kernel<<<(EE + 255) / 256, 256, 0, stream>>>(ei, deg);
    scanA_kernel<<<SC_NB, 256, 0, stream>>>(deg, offs, bsum);
    scanB_kernel<<<1, 128, 0, stream>>>(bsum);
    scanC_kernel<<<(NN + 255) / 256, 256, 0, stream>>>(offs, bsum, cursor);
    scatter_kernel<<<(EE + 255) / 256, 256, 0, stream>>>(ei, cursor, ssrc);
    attn_kernel<<<NN / 4, 256, 0, stream>>>(Q, KV, S, offs, deg, ssrc,
                                            W1, b1, W2, b2, W3, b3, out);
}